// Round 20
// baseline (193.983 us; speedup 1.0000x reference)
//
#include <hip/hip_runtime.h>
#include <cstdint>
#include <cmath>

#define DEVINL __device__ __forceinline__

// Split-bf16 buffers are ROW-INTERLEAVED: logical [R x K] stored as R rows of
// 2K shorts: [ hi[0..K) | lo[0..K) ]. Feature pipeline is MASK-COMPACTED.

using f32x4  = __attribute__((ext_vector_type(4))) float;
using bf16x8 = __attribute__((ext_vector_type(8))) __bf16;
using u16x8  = __attribute__((ext_vector_type(8))) unsigned short;
using u16x4  = __attribute__((ext_vector_type(4))) unsigned short;
using fl4    = __attribute__((ext_vector_type(4))) float;

DEVINL float bf2f(unsigned short h) {
    unsigned int u = ((unsigned int)h) << 16;
    float f; __builtin_memcpy(&f, &u, 4); return f;
}
DEVINL unsigned short f2bf(float f) {
    unsigned int u; __builtin_memcpy(&u, &f, 4);
    u += 0x7FFFu + ((u >> 16) & 1u);   // RNE
    return (unsigned short)(u >> 16);
}
DEVINL float sqrt_raw(float x) {
    float r; asm("v_sqrt_f32 %0, %1" : "=v"(r) : "v"(x)); return r;
}

DEVINL void gload_lds16(const unsigned short* g, unsigned short* l) {
    __builtin_amdgcn_global_load_lds(
        (__attribute__((address_space(1))) void*)g,
        (__attribute__((address_space(3))) void*)l,
        16, 0, 0);
}

// ---------------------------------------------------------------------------
// Preproc (ONE launch, 4 independent segments):
//   [0,2048)      zero-fill attn output
//   [2048,2056)   per-batch mask scan
//   [2056,6664)   transpose+split Wq,Wk (row-interleaved)
//   [6664,12232)  GRU-path conversions Wih/Whh/slots/Wv -> bf16
__global__ __launch_bounds__(256)
void preproc(const int* __restrict__ mask, int* __restrict__ idx,
             int* __restrict__ cnt, int* __restrict__ cpad,
             float* __restrict__ zp,
             const float* __restrict__ Wq, const float* __restrict__ Wk,
             unsigned short* __restrict__ WqT_i, unsigned short* __restrict__ WkT_i,
             const float* __restrict__ Wih, const float* __restrict__ Whh,
             const float* __restrict__ sl,  const float* __restrict__ Wv,
             unsigned short* __restrict__ Wihb, unsigned short* __restrict__ Whhb,
             unsigned short* __restrict__ slb,  unsigned short* __restrict__ Wvb)
{
    if (blockIdx.x < 2048) {
        const int i = blockIdx.x * 256 + threadIdx.x;
        fl4 z = {0.f, 0.f, 0.f, 0.f};
        *(fl4*)(zp + (long)i * 4) = z;
        return;
    }
    if (blockIdx.x < 2056) {
        constexpr int NB = 1024;
        const int b = (blockIdx.x - 2048) * 4 + (threadIdx.x >> 6);
        const int lane = threadIdx.x & 63;
        if (b >= 32) return;
        const int* mrow = mask + b * NB;
        int loc[16]; int lsum = 0;
#pragma unroll
        for (int i = 0; i < 16; ++i) { loc[i] = mrow[lane * 16 + i] != 0; lsum += loc[i]; }
        int pre = lsum;
#pragma unroll
        for (int o = 1; o < 64; o <<= 1) {
            int t = __shfl_up(pre, o);
            if (lane >= o) pre += t;
        }
        const int total = __shfl(pre, 63);
        pre -= lsum;
        int* ib = idx + b * NB;
        int p = pre;
#pragma unroll
        for (int i = 0; i < 16; ++i) if (loc[i]) ib[p++] = lane * 16 + i;
        if (lane == 0) {
            cnt[b] = total;
            int cp = (total + 63) & ~63;
            cpad[b] = cp < 64 ? 64 : cp;
        }
        return;
    }
    if (blockIdx.x < 6664) {
        constexpr int S = 768 * 768;
        const int o = (blockIdx.x - 2056) * 256 + threadIdx.x;
        if (o >= 2 * S) return;
        const float* x; unsigned short* y; int i;
        if (o < S) { x = Wq; y = WqT_i; i = o; }
        else       { x = Wk; y = WkT_i; i = o - S; }
        const int e = i / 768, d = i - e * 768;
        const float v = x[d * 768 + e];
        const unsigned short h = f2bf(v);
        y[(long)e * 1536 + d]       = h;
        y[(long)e * 1536 + 768 + d] = f2bf(v - bf2f(h));
        return;
    }
    // conv2 segment
    constexpr int S1 = 3 * 768 * 768;
    constexpr int S2 = S1 + 3 * 768 * 768;
    constexpr int S3 = S2 + 32 * 64 * 768;
    constexpr int S4 = S3 + 768 * 768;
    const int i = ((blockIdx.x - 6664) * 256 + threadIdx.x) * 4;
    if (i >= S4) return;
    const float* src; unsigned short* dst; int off;
    if (i < S1)      { src = Wih; dst = Wihb; off = i; }
    else if (i < S2) { src = Whh; dst = Whhb; off = i - S1; }
    else if (i < S3) { src = sl;  dst = slb;  off = i - S2; }
    else             { src = Wv;  dst = Wvb;  off = i - S3; }
    fl4 v = *(const fl4*)(src + off);
    u16x4 o;
#pragma unroll
    for (int j = 0; j < 4; ++j) o[j] = f2bf(v[j]);
    *(u16x4*)(dst + off) = o;
}

// ---------------------------------------------------------------------------
// Split-bf16 3-pass GEMM over row-interleaved A and B (split out).
template<int BM, int BN, int WAVES_M, int WAVES_N>
__global__ __launch_bounds__(256)
void gemm_bt3s(const unsigned short* __restrict__ AB, const unsigned short* __restrict__ BB,
               unsigned short* __restrict__ out1,
               int N, int K, long sA, long sB, float alpha)
{
    constexpr int BK = 32;
    constexpr int WM = BM / WAVES_M, WN = BN / WAVES_N;
    constexpr int MT = WM / 16, NT = WN / 16;
    __shared__ alignas(16) unsigned short Ash[BM * BK], Asl[BM * BK];
    __shared__ alignas(16) unsigned short Bsh[BN * BK], Bsl[BN * BK];

    const int bz = blockIdx.z;
    const int row0 = blockIdx.y * BM, col0 = blockIdx.x * BN;
    AB += (long)bz * sA;
    BB += (long)bz * sB;
    const int tid = threadIdx.x, l = tid & 63, w = tid >> 6;
    const int wm = w / WAVES_N, wn = w % WAVES_N;
    const int fr = l & 15, fq = l >> 4;

    f32x4 acc[MT][NT] = {};
    constexpr int ACALLS = (BM * BK) / (256 * 8);
    constexpr int BCALLS = (BN * BK) / (256 * 8);

    for (int kt = 0; kt < K; kt += BK) {
#pragma unroll
        for (int c = 0; c < ACALLS; ++c) {
            const int e = (c * 256 + tid) * 8;
            const long rb = (long)(row0 + (e >> 5)) * (2 * K) + kt + (e & 31);
            gload_lds16(AB + rb, &Ash[e]);
            gload_lds16(AB + rb + K, &Asl[e]);
        }
#pragma unroll
        for (int c = 0; c < BCALLS; ++c) {
            const int e = (c * 256 + tid) * 8;
            const long rb = (long)(col0 + (e >> 5)) * (2 * K) + kt + (e & 31);
            gload_lds16(BB + rb, &Bsh[e]);
            gload_lds16(BB + rb + K, &Bsl[e]);
        }
        __syncthreads();

        bf16x8 afh[MT], afl[MT], bfh[NT], bfl[NT];
#pragma unroll
        for (int m = 0; m < MT; ++m) {
            const int o = (wm * WM + m * 16 + fr) * BK + fq * 8;
            afh[m] = __builtin_bit_cast(bf16x8, *(const u16x8*)&Ash[o]);
            afl[m] = __builtin_bit_cast(bf16x8, *(const u16x8*)&Asl[o]);
        }
#pragma unroll
        for (int n = 0; n < NT; ++n) {
            const int o = (wn * WN + n * 16 + fr) * BK + fq * 8;
            bfh[n] = __builtin_bit_cast(bf16x8, *(const u16x8*)&Bsh[o]);
            bfl[n] = __builtin_bit_cast(bf16x8, *(const u16x8*)&Bsl[o]);
        }
#pragma unroll
        for (int m = 0; m < MT; ++m)
#pragma unroll
            for (int n = 0; n < NT; ++n) {
                acc[m][n] = __builtin_amdgcn_mfma_f32_16x16x32_bf16(afh[m], bfh[n], acc[m][n], 0, 0, 0);
                acc[m][n] = __builtin_amdgcn_mfma_f32_16x16x32_bf16(afh[m], bfl[n], acc[m][n], 0, 0, 0);
                acc[m][n] = __builtin_amdgcn_mfma_f32_16x16x32_bf16(afl[m], bfh[n], acc[m][n], 0, 0, 0);
            }
        __syncthreads();
    }

#pragma unroll
    for (int m = 0; m < MT; ++m) {
        const int gr = row0 + wm * WM + m * 16 + fq * 4;
#pragma unroll
        for (int n = 0; n < NT; ++n) {
            const int gc = col0 + wn * WN + n * 16 + fr;
#pragma unroll
            for (int j = 0; j < 4; ++j) {
                const float v = acc[m][n][j] * alpha;
                const long rb = (long)(gr + j) * (2 * N) + gc;
                const unsigned short h = f2bf(v);
                out1[rb] = h;
                out1[rb + N] = f2bf(v - bf2f(h));
            }
        }
    }
}

// ---------------------------------------------------------------------------
// FUSED logits-GEMM + normmax. Grid (N/64, B).
__global__ __launch_bounds__(256)
void logits_normmax(const unsigned short* __restrict__ qk_i,
                    const unsigned short* __restrict__ f_i,
                    const int* __restrict__ idx, const int* __restrict__ cnt,
                    const int* __restrict__ cpad,
                    float* __restrict__ attn_f32, unsigned short* __restrict__ attn_b16)
{
    constexpr int BK = 32, K = 768, C = 64, N = 1024;
    constexpr float alpha = 0.03608439182435161f;   // 1/sqrt(768)
    const int b = blockIdx.y;
    const int col0 = blockIdx.x * 64;
    if (col0 >= cpad[b]) return;

    __shared__ alignas(16) unsigned short Ash[64 * BK], Asl[64 * BK];
    __shared__ alignas(16) unsigned short Bsh[64 * BK], Bsl[64 * BK];
    __shared__ float lgS[64][65];

    const unsigned short* AB = qk_i + (long)b * C * 2 * K;
    const unsigned short* BB = f_i + (long)b * N * 2 * K;
    const int tid = threadIdx.x, l = tid & 63, w = tid >> 6;
    const int wm = w >> 1, wn = w & 1;
    const int fr = l & 15, fq = l >> 4;

    f32x4 acc[2][2] = {};

    for (int kt = 0; kt < K; kt += BK) {
        {
            const int e = tid * 8;
            const long ra = (long)(e >> 5) * (2 * K) + kt + (e & 31);
            gload_lds16(AB + ra, &Ash[e]);
            gload_lds16(AB + ra + K, &Asl[e]);
            const long rb = (long)(col0 + (e >> 5)) * (2 * K) + kt + (e & 31);
            gload_lds16(BB + rb, &Bsh[e]);
            gload_lds16(BB + rb + K, &Bsl[e]);
        }
        __syncthreads();

        bf16x8 afh[2], afl[2], bfh[2], bfl[2];
#pragma unroll
        for (int m = 0; m < 2; ++m) {
            const int o = (wm * 32 + m * 16 + fr) * BK + fq * 8;
            afh[m] = __builtin_bit_cast(bf16x8, *(const u16x8*)&Ash[o]);
            afl[m] = __builtin_bit_cast(bf16x8, *(const u16x8*)&Asl[o]);
        }
#pragma unroll
        for (int n = 0; n < 2; ++n) {
            const int o = (wn * 32 + n * 16 + fr) * BK + fq * 8;
            bfh[n] = __builtin_bit_cast(bf16x8, *(const u16x8*)&Bsh[o]);
            bfl[n] = __builtin_bit_cast(bf16x8, *(const u16x8*)&Bsl[o]);
        }
#pragma unroll
        for (int m = 0; m < 2; ++m)
#pragma unroll
            for (int n = 0; n < 2; ++n) {
                acc[m][n] = __builtin_amdgcn_mfma_f32_16x16x32_bf16(afh[m], bfh[n], acc[m][n], 0, 0, 0);
                acc[m][n] = __builtin_amdgcn_mfma_f32_16x16x32_bf16(afh[m], bfl[n], acc[m][n], 0, 0, 0);
                acc[m][n] = __builtin_amdgcn_mfma_f32_16x16x32_bf16(afl[m], bfh[n], acc[m][n], 0, 0, 0);
            }
        __syncthreads();
    }

#pragma unroll
    for (int m = 0; m < 2; ++m) {
        const int lr = wm * 32 + m * 16 + fq * 4;
#pragma unroll
        for (int n = 0; n < 2; ++n) {
            const int lc = wn * 32 + n * 16 + fr;
#pragma unroll
            for (int j = 0; j < 4; ++j) lgS[lr + j][lc] = acc[m][n][j] * alpha;
        }
    }
    __syncthreads();

    const int jl = w * 16 + (l & 15);
    const int cb = (l >> 4) * 16;
    const int j = col0 + jl;
    const bool valid = j < cnt[b];

    float z[16];
#pragma unroll
    for (int i = 0; i < 16; ++i) z[i] = valid ? lgS[cb + i][jl] : 0.f;

    float mx = z[0];
#pragma unroll
    for (int i = 1; i < 16; ++i) mx = fmaxf(mx, z[i]);
    mx = fmaxf(mx, __shfl_xor(mx, 16));
    mx = fmaxf(mx, __shfl_xor(mx, 32));

    float lo = mx - 1.f, hi = mx;
    for (int it = 0; it < 34; ++it) {
        const float tau = 0.5f * (lo + hi);
        float f = 0.f;
#pragma unroll
        for (int i = 0; i < 16; ++i) {
            const float u = fmaxf(z[i] - tau, 0.f);
            f += u * sqrt_raw(sqrt_raw(u));       // u^(5/4)
        }
        f += __shfl_xor(f, 16);
        f += __shfl_xor(f, 32);
        if (f >= 1.f) lo = tau; else hi = tau;
    }
    const float tau = 0.5f * (lo + hi);
    float sv[16]; float ss = 0.f;
#pragma unroll
    for (int i = 0; i < 16; ++i) {
        const float u = fmaxf(z[i] - tau, 0.f);
        sv[i] = sqrt_raw(sqrt_raw(u));            // u^(1/4)
        ss += sv[i];
    }
    ss += __shfl_xor(ss, 16);
    ss += __shfl_xor(ss, 32);
    const float inv = 1.f / ss;
    const long base = (long)b * C * N + j;
    const int n_orig = valid ? idx[(b << 10) + j] : 0;
#pragma unroll
    for (int i = 0; i < 16; ++i) {
        const float a = valid ? sv[i] * inv : 0.f;
        attn_b16[base + (long)(cb + i) * N] = f2bf(a);
        if (valid) attn_f32[(long)b * C * N + (long)(cb + i) * N + n_orig] = a;
    }
}

// ---------------------------------------------------------------------------
// Plain bf16 GEMM: C[M,N] = alpha * A[M,K] @ B[N,K]^T
template<int BM, int BN, int WAVES_M, int WAVES_N, bool OUT_F32>
__global__ __launch_bounds__(256)
void gemm_bt(const unsigned short* __restrict__ A,
             const unsigned short* __restrict__ B,
             void* __restrict__ Cv,
             int N, int K, long sA, long sB, long sC, float alpha)
{
    constexpr int BK = 32;
    constexpr int WM = BM / WAVES_M, WN = BN / WAVES_N;
    constexpr int MT = WM / 16, NT = WN / 16;
    __shared__ alignas(16) unsigned short As[BM * BK];
    __shared__ alignas(16) unsigned short Bs[BN * BK];

    const int bz = blockIdx.z;
    A += (long)bz * sA;
    B += (long)bz * sB;
    const int row0 = blockIdx.y * BM, col0 = blockIdx.x * BN;
    const int tid = threadIdx.x, l = tid & 63, w = tid >> 6;
    const int wm = w / WAVES_N, wn = w % WAVES_N;
    const int fr = l & 15, fq = l >> 4;

    f32x4 acc[MT][NT] = {};
    constexpr int ACALLS = (BM * BK) / (256 * 8);
    constexpr int BCALLS = (BN * BK) / (256 * 8);

    for (int kt = 0; kt < K; kt += BK) {
#pragma unroll
        for (int c = 0; c < ACALLS; ++c) {
            const int e = (c * 256 + tid) * 8;
            gload_lds16(A + (long)(row0 + (e >> 5)) * K + kt + (e & 31), &As[e]);
        }
#pragma unroll
        for (int c = 0; c < BCALLS; ++c) {
            const int e = (c * 256 + tid) * 8;
            gload_lds16(B + (long)(col0 + (e >> 5)) * K + kt + (e & 31), &Bs[e]);
        }
        __syncthreads();

        bf16x8 af[MT], bfr[NT];
#pragma unroll
        for (int m = 0; m < MT; ++m)
            af[m] = __builtin_bit_cast(bf16x8, *(const u16x8*)&As[(wm * WM + m * 16 + fr) * BK + fq * 8]);
#pragma unroll
        for (int n = 0; n < NT; ++n)
            bfr[n] = __builtin_bit_cast(bf16x8, *(const u16x8*)&Bs[(wn * WN + n * 16 + fr) * BK + fq * 8]);
#pragma unroll
        for (int m = 0; m < MT; ++m)
#pragma unroll
            for (int n = 0; n < NT; ++n)
                acc[m][n] = __builtin_amdgcn_mfma_f32_16x16x32_bf16(af[m], bfr[n], acc[m][n], 0, 0, 0);
        __syncthreads();
    }

#pragma unroll
    for (int m = 0; m < MT; ++m) {
        const int gr = row0 + wm * WM + m * 16 + fq * 4;
#pragma unroll
        for (int n = 0; n < NT; ++n) {
            const int gc = col0 + wn * WN + n * 16 + fr;
#pragma unroll
            for (int j = 0; j < 4; ++j) {
                const float v = acc[m][n][j] * alpha;
                if (OUT_F32) ((float*)Cv)[(long)bz * sC + (long)(gr + j) * N + gc] = v;
                else ((unsigned short*)Cv)[(long)bz * sC + (long)(gr + j) * N + gc] = f2bf(v);
            }
        }
    }
}

// ---------------------------------------------------------------------------
// Fused gate-GEMM + GRU (K=768), 512 threads, 64-row x 128-gate-col tiles.
// Grid (D/128, B*C/64): col0 in [0,768); kernel covers all 3 gates internally.
__global__ __launch_bounds__(512)
void gemm_gru(const unsigned short* __restrict__ updb, const unsigned short* __restrict__ slb,
              const unsigned short* __restrict__ Wihb, const unsigned short* __restrict__ Whhb,
              const float* __restrict__ b_ih, const float* __restrict__ b_hh,
              const float* __restrict__ h, float* __restrict__ out)
{
    constexpr int BK = 32, Kd = 768, Dd = 768;
    __shared__ alignas(16) unsigned short Au[64 * BK], As[64 * BK];
    __shared__ alignas(16) unsigned short Bi[3][128 * BK], Bh[3][128 * BK];

    const int row0 = blockIdx.y * 64, col0 = blockIdx.x * 128;
    const int tid = threadIdx.x, l = tid & 63, w = tid >> 6;   // w in [0,8)
    const int wm = w >> 2, wn = w & 3;                          // 2 x 4 waves; WM=WN=32
    const int fr = l & 15, fq = l >> 4;

    f32x4 ai[3][2][2] = {}, ah[3][2][2] = {};

    for (int kt = 0; kt < Kd; kt += BK) {
        {
            // A staging: waves 0-3 -> Au, waves 4-7 -> As (2048 shorts each)
            const int e2 = (tid & 255) * 8;
            const long ra = (long)(row0 + (e2 >> 5)) * Kd + kt + (e2 & 31);
            if (tid < 256) gload_lds16(updb + ra, &Au[e2]);
            else           gload_lds16(slb + ra, &As[e2]);
            // B staging: 6 gate tiles of 128x32 = 4096 shorts = one call each
            const int e = tid * 8;
            const int brow = e >> 5;
#pragma unroll
            for (int g = 0; g < 3; ++g) {
                const long wb = (long)(g * Dd + col0 + brow) * Kd + kt + (e & 31);
                gload_lds16(Wihb + wb, &Bi[g][e]);
                gload_lds16(Whhb + wb, &Bh[g][e]);
            }
        }
        __syncthreads();

        bf16x8 au[2], as_[2], bi[3][2], bh[3][2];
#pragma unroll
        for (int m = 0; m < 2; ++m) {
            const int o = (wm * 32 + m * 16 + fr) * BK + fq * 8;
            au[m]  = __builtin_bit_cast(bf16x8, *(const u16x8*)&Au[o]);
            as_[m] = __builtin_bit_cast(bf16x8, *(const u16x8*)&As[o]);
        }
#pragma unroll
        for (int n = 0; n < 2; ++n) {
            const int o = (wn * 32 + n * 16 + fr) * BK + fq * 8;
#pragma unroll
            for (int g = 0; g < 3; ++g) {
                bi[g][n] = __builtin_bit_cast(bf16x8, *(const u16x8*)&Bi[g][o]);
                bh[g][n] = __builtin_bit_cast(bf16x8, *(const u16x8*)&Bh[g][o]);
            }
        }
#pragma unroll
        for (int g = 0; g < 3; ++g)
#pragma unroll
            for (int m = 0; m < 2; ++m)
#pragma unroll
                for (int n = 0; n < 2; ++n) {
                    ai[g][m][n] = __builtin_amdgcn_mfma_f32_16x16x32_bf16(au[m],  bi[g][n], ai[g][m][n], 0, 0, 0);
                    ah[g][m][n] = __builtin_amdgcn_mfma_f32_16x16x32_bf16(as_[m], bh[g][n], ah[g][m][n], 0, 0, 0);
                }
        __syncthreads();
    }

#pragma unroll
    for (int m = 0; m < 2; ++m) {
        const int gr = row0 + wm * 32 + m * 16 + fq * 4;
#pragma unroll
        for (int n = 0; n < 2; ++n) {
            const int gc = col0 + wn * 32 + n * 16 + fr;
            const float bir = b_ih[gc],        bhr = b_hh[gc];
            const float biz = b_ih[Dd + gc],   bhz = b_hh[Dd + gc];
            const float bin = b_ih[2*Dd + gc], bhn = b_hh[2*Dd + gc];
#pragma unroll
            for (int j = 0; j < 4; ++j) {
                const float r  = 1.f / (1.f + expf(-(ai[0][m][n][j] + bir + ah[0][m][n][j] + bhr)));
                const float zg = 1.f / (1.f + expf(-(ai[1][m][n][j] + biz + ah[1][m][n][j] + bhz)));
                const float ng = tanhf(ai[2][m][n][j] + bin + r * (ah[2][m][n][j] + bhn));
                const long idx = (long)(gr + j) * Dd + gc;
                out[idx] = (1.f - zg) * ng + zg * h[idx];
            }
        }
    }
}

// ---------------------------------------------------------------------------
// P GEMM, compacted-K, fused row-sum normalization.
template<int BM, int BN, int WAVES_M, int WAVES_N>
__global__ __launch_bounds__(256)
void gemm_nt_rs(const unsigned short* __restrict__ A,
                const unsigned short* __restrict__ Bm,
                unsigned short* __restrict__ C,
                const int* __restrict__ cpad,
                int N, int Kmax, long sA, long sB, long sC)
{
    constexpr int BK = 32;
    constexpr int WM = BM / WAVES_M, WN = BN / WAVES_N;
    constexpr int MT = WM / 16, NT = WN / 16;
    __shared__ alignas(16) unsigned short As[BM * BK];
    __shared__ alignas(16) unsigned short Bs[BN * BK];
    __shared__ float rsums[BM];

    const int bz = blockIdx.z;
    const int Keff = cpad[bz];
    A += (long)bz * sA;
    Bm += (long)bz * sB;
    const int row0 = blockIdx.y * BM, col0 = blockIdx.x * BN;
    const int tid = threadIdx.x, l = tid & 63, w = tid >> 6;
    const int wm = w / WAVES_N, wn = w % WAVES_N;
    const int fr = l & 15, fq = l >> 4;

    f32x4 acc[MT][NT] = {};
    float rsum = 0.f;
    constexpr int ACALLS = (BM * BK) / (256 * 8);
    constexpr int TPR = BN / 8;
    constexpr int RPP = 256 / TPR;
    const int br = tid / TPR, bc8 = (tid % TPR) * 8;

    for (int kt = 0; kt < Keff; kt += BK) {
#pragma unroll
        for (int c = 0; c < ACALLS; ++c) {
            const int e = (c * 256 + tid) * 8;
            gload_lds16(A + (long)(row0 + (e >> 5)) * Kmax + kt + (e & 31), &As[e]);
        }
#pragma unroll
        for (int p = 0; p < BK / RPP; ++p) {
            const int r = p * RPP + br;
            u16x8 vv = *(const u16x8*)(Bm + (long)(kt + r) * (2 * N) + col0 + bc8);
#pragma unroll
            for (int j = 0; j < 8; ++j) Bs[(bc8 + j) * BK + r] = vv[j];
        }
        __syncthreads();

        if (tid < BM) {
#pragma unroll
            for (int kk = 0; kk < BK / 8; ++kk) {
                u16x8 vv = *(const u16x8*)&As[tid * BK + kk * 8];
#pragma unroll
                for (int j = 0; j < 8; ++j) rsum += bf2f(vv[j]);
            }
        }

        bf16x8 af[MT], bfr[NT];
#pragma unroll
        for (int m = 0; m < MT; ++m)
            af[m] = __builtin_bit_cast(bf16x8, *(const u16x8*)&As[(wm * WM + m * 16 + fr) * BK + fq * 8]);
#pragma unroll
        for (int n = 0; n < NT; ++n)
            bfr[n] = __builtin_bit_cast(bf16x8, *(const u16x8*)&Bs[(wn * WN + n * 16 + fr) * BK + fq * 8]);
#pragma unroll
        for (int m = 0; m < MT; ++m)
#pragma unroll
            for (int n = 0; n < NT; ++n)
                acc[m][n] = __builtin_amdgcn_mfma_f32_16x16x32_bf16(af[m], bfr[n], acc[m][n], 0, 0, 0);
        __syncthreads();
    }

    if (tid < BM) rsums[tid] = rsum;
    __syncthreads();

#pragma unroll
    for (int m = 0; m < MT; ++m) {
        const int lr = wm * WM + m * 16 + fq * 4;
        const int gr = row0 + lr;
#pragma unroll
        for (int n = 0; n < NT; ++n) {
            const int gc = col0 + wn * WN + n * 16 + fr;
#pragma unroll
            for (int j = 0; j < 4; ++j) {
                const float inv = 1.f / (rsums[lr + j] + 1e-8f);
                C[(long)bz * sC + (long)(gr + j) * N + gc] = f2bf(acc[m][n][j] * inv);
            }
        }
    }
}

// ---------------------------------------------------------------------------
// Fused, mask-compacted LayerNorm (features + slots), f32 -> interleaved split.
__global__ __launch_bounds__(256)
void ln_fused_c(const float* __restrict__ xf, const float* __restrict__ gf,
                const float* __restrict__ bf,
                unsigned short* __restrict__ fi,
                const float* __restrict__ xs, const float* __restrict__ gs,
                const float* __restrict__ bs,
                unsigned short* __restrict__ si,
                const int* __restrict__ idx, const int* __restrict__ cnt,
                const int* __restrict__ cpad, int nrows_f)
{
    constexpr int D = 768;
    const int lane = threadIdx.x & 63;
    long row = (long)blockIdx.x * 4 + (threadIdx.x >> 6);
    const float *x, *g, *bb_;
    long srow;
    if (row < nrows_f) {
        const int b = (int)(row >> 10), j = (int)(row & 1023);
        if (j >= cpad[b]) return;
        srow = row;
        unsigned short* yr = fi + srow * (2 * D);
        if (j >= cnt[b]) {
            u16x8 z = {};
            unsigned short* p = yr + lane * 24;
            *(u16x8*)p = z; *(u16x8*)(p + 8) = z; *(u16x8*)(p + 16) = z;
            return;
        }
        const int n = idx[(b << 10) + j];
        x = xf + ((long)(b << 10) + n) * D;
        g = gf; bb_ = bf;
    } else {
        srow = row - nrows_f;
        x = xs + srow * D;
        g = gs; bb_ = bs;
    }

    const int eA = lane * 8;
    const int eB = 512 + lane * 8;
    float v[16];
    {
        fl4 a = *(const fl4*)(x + eA);
        fl4 b = *(const fl4*)(x + eA + 4);
#pragma unroll
        for (int j = 0; j < 4; ++j) { v[j] = a[j]; v[4 + j] = b[j]; }
    }
    if (lane < 32) {
        fl4 a = *(const fl4*)(x + eB);
        fl4 b = *(const fl4*)(x + eB + 4);
#pragma unroll
        for (int j = 0; j < 4; ++j) { v[8 + j] = a[j]; v[12 + j] = b[j]; }
    }
    float s = 0.f, s2 = 0.f;
#pragma unroll
    for (int j = 0; j < 8; ++j) { s += v[j]; s2 += v[j] * v[j]; }
    if (lane < 32) {
#pragma unroll
        for (int j = 8; j < 16; ++j) { s += v[j]; s2 += v[j] * v[j]; }
    }
#pragma unroll
    for (int o = 1; o < 64; o <<= 1) { s += __shfl_xor(s, o); s2 += __shfl_xor(s2, o); }
    const float mu  = s / (float)D;
    const float var = s2 / (float)D - mu * mu;
    const float r   = rsqrtf(var + 1e-5f);

    unsigned short* yr = (row < nrows_f ? fi : si) + srow * (2 * D);
    {
        fl4 g0 = *(const fl4*)(g + eA), g1 = *(const fl4*)(g + eA + 4);
        fl4 b0 = *(const fl4*)(bb_ + eA), b1 = *(const fl4*)(bb_ + eA + 4);
        u16x8 oh, ol;
#pragma unroll
        for (int j = 0; j < 8; ++j) {
            const float gg = (j < 4) ? g0[j] : g1[j - 4];
            const float be = (j < 4) ? b0[j] : b1[j - 4];
            const float yv = (v[j] - mu) * r * gg + be;
            oh[j] = f2bf(yv);
            ol[j] = f2bf(yv - bf2f(oh[j]));
        }
        *(u16x8*)(yr + eA) = oh;
        *(u16x8*)(yr + D + eA) = ol;
    }
    if (lane < 32) {
        fl4 g0 = *(const fl4*)(g + eB), g1 = *(const fl4*)(g + eB + 4);
        fl4 b0 = *(const fl4*)(bb_ + eB), b1 = *(const fl4*)(bb_ + eB + 4);
        u16x8 oh, ol;
#pragma unroll
        for (int j = 0; j < 8; ++j) {
            const float gg = (j < 4) ? g0[j] : g1[j - 4];
            const float be = (j < 4) ? b0[j] : b1[j - 4];
            const float yv = (v[8 + j] - mu) * r * gg + be;
            oh[j] = f2bf(yv);
            ol[j] = f2bf(yv - bf2f(oh[j]));
        }
        *(u16x8*)(yr + eB) = oh;
        *(u16x8*)(yr + D + eB) = ol;
    }
}

extern "C" void kernel_launch(void* const* d_in, const int* in_sizes, int n_in,
                              void* d_out, int out_size, void* d_ws, size_t ws_size,
                              hipStream_t stream)
{
    const float* features = (const float*)d_in[0];
    const float* slots    = (const float*)d_in[1];
    const int*   mask     = (const int*)d_in[2];
    const float* lnf_g = (const float*)d_in[3];
    const float* lnf_b = (const float*)d_in[4];
    const float* lns_g = (const float*)d_in[5];
    const float* lns_b = (const float*)d_in[6];
    const float* Wk  = (const float*)d_in[7];
    const float* Wv  = (const float*)d_in[8];
    const float* Wq  = (const float*)d_in[9];
    const float* Wih = (const float*)d_in[10];
    const float* Whh = (const float*)d_in[11];
    const float* bih = (const float*)d_in[12];
    const float* bhh = (const float*)d_in[13];

    constexpr int B = 32, N = 1024, C = 64, D = 768;
    char* ws = (char*)d_ws;
    // ---- workspace layout, peak ~132.0 MB
    unsigned short* f_i  = (unsigned short*)(ws + 0);          // compacted f, 100,663,296
    unsigned short* updb = (unsigned short*)(ws + 57671680);   // [upd gemm .. gru] (f_i dead)
    unsigned short* Wihb = (unsigned short*)(ws + 100663296);  //  3,538,944
    unsigned short* Whhb = (unsigned short*)(ws + 104202240);  //  3,538,944
    unsigned short* Wvb  = (unsigned short*)(ws + 107741184);  //  1,179,648 -> 108,920,832
    unsigned short* s_i    = (unsigned short*)(ws + 109051904); //  6,291,456 [LN .. qk gemm]
    unsigned short* ab16   = (unsigned short*)(ws + 109051904); //  4,194,304 (s_i dead)
    unsigned short* qk_i   = (unsigned short*)(ws + 115343360); //  6,291,456 [qk .. logits]
    unsigned short* Pbf    = (unsigned short*)(ws + 115343360); //  3,145,728 (qk_i dead)
    unsigned short* WqT_i  = (unsigned short*)(ws + 121634816); //  2,359,296
    unsigned short* WkT_i  = (unsigned short*)(ws + 123994112); //  2,359,296
    unsigned short* M_i    = (unsigned short*)(ws + 126353408); //  2,359,296
    int*            idx    = (int*)(ws + 128712704);            //    131,072
    int*            cnt    = (int*)(ws + 128843776);            //        128
    int*            cpad   = (int*)(ws + 128843904);            //        128
    unsigned short* slb    = (unsigned short*)(ws + 128844032); //  3,145,728 -> 131,989,760

    float* out_slots = (float*)d_out;
    float* out_attn  = out_slots + (long)B * C * D;

    // preproc: zfill + mask scan + Wq/Wk transpose-split + GRU-weight convert
    preproc<<<12232, 256, 0, stream>>>(
        mask, idx, cnt, cpad, out_attn, Wq, Wk, WqT_i, WkT_i,
        Wih, Whh, slots, Wv, Wihb, Whhb, slb, Wvb);

    // compacted LN (features) + LN (slots)
    ln_fused_c<<<(B * N + B * C) / 4, 256, 0, stream>>>(
        features, lnf_g, lnf_b, f_i,
        slots, lns_g, lns_b, s_i,
        idx, cnt, cpad, B * N);

    // M[j,i] = sum_k Wk[k,j]*Wq[k,i]  [768 x 768], interleaved out
    gemm_bt3s<64, 64, 2, 2><<<dim3(D / 64, D / 64, 1), 256, 0, stream>>>(
        WkT_i, WqT_i, M_i, D, D, 0, 0, 1.f);
    // qk = s @ M^T   [2048 x 768], interleaved out
    gemm_bt3s<64, 64, 2, 2><<<dim3(D / 64, (B * C) / 64, 1), 256, 0, stream>>>(
        s_i, M_i, qk_i, D, D, 0, 0, 1.f);

    // FUSED logits + normmax -> scattered f32 attn (d_out) + compacted bf16
    logits_normmax<<<dim3(N / 64, B), 256, 0, stream>>>(
        qk_i, f_i, idx, cnt, cpad, out_attn, ab16);

    // P[b] = diag(1/(rowsum+eps)) * attñ_b @ f̃_b(hi)   [64 x 768], K=cpad(b)
    gemm_nt_rs<64, 64, 2, 2><<<dim3(D / 64, 1, B), 256, 0, stream>>>(
        ab16, f_i, Pbf, cpad, D, N, (long)C * N, (long)N * 2 * D, (long)C * D);

    // upd = P @ Wv^T   [2048 x 768]
    gemm_bt<64, 64, 2, 2, false><<<dim3(D / 64, (B * C) / 64, 1), 256, 0, stream>>>(
        Pbf, Wvb, updb, D, D, 0, 0, 0, 1.f);

    // fused gate-GEMM + GRU -> out_slots (64x128 tiles, 512 threads)
    gemm_gru<<<dim3(D / 128, (B * C) / 64), 512, 0, stream>>>(
        updb, slb, Wihb, Whhb, bih, bhh, slots, out_slots);
}

// Round 21
// 184.897 us; speedup vs baseline: 1.0491x; 1.0491x over previous
//
#include <hip/hip_runtime.h>
#include <cstdint>
#include <cmath>

#define DEVINL __device__ __forceinline__

// Split-bf16 buffers are ROW-INTERLEAVED: logical [R x K] stored as R rows of
// 2K shorts: [ hi[0..K) | lo[0..K) ]. Feature pipeline is MASK-COMPACTED.

using f32x4  = __attribute__((ext_vector_type(4))) float;
using bf16x8 = __attribute__((ext_vector_type(8))) __bf16;
using u16x8  = __attribute__((ext_vector_type(8))) unsigned short;
using u16x4  = __attribute__((ext_vector_type(4))) unsigned short;
using fl4    = __attribute__((ext_vector_type(4))) float;

DEVINL float bf2f(unsigned short h) {
    unsigned int u = ((unsigned int)h) << 16;
    float f; __builtin_memcpy(&f, &u, 4); return f;
}
DEVINL unsigned short f2bf(float f) {
    unsigned int u; __builtin_memcpy(&u, &f, 4);
    u += 0x7FFFu + ((u >> 16) & 1u);   // RNE
    return (unsigned short)(u >> 16);
}
DEVINL float sqrt_raw(float x) {
    float r; asm("v_sqrt_f32 %0, %1" : "=v"(r) : "v"(x)); return r;
}

DEVINL void gload_lds16(const unsigned short* g, unsigned short* l) {
    __builtin_amdgcn_global_load_lds(
        (__attribute__((address_space(1))) void*)g,
        (__attribute__((address_space(3))) void*)l,
        16, 0, 0);
}

// ---------------------------------------------------------------------------
// Preproc (ONE launch, 4 independent segments):
//   [0,2048)      zero-fill attn output
//   [2048,2056)   per-batch mask scan
//   [2056,6664)   transpose+split Wq,Wk (row-interleaved)
//   [6664,12232)  GRU-path conversions Wih/Whh/slots/Wv -> bf16
__global__ __launch_bounds__(256)
void preproc(const int* __restrict__ mask, int* __restrict__ idx,
             int* __restrict__ cnt, int* __restrict__ cpad,
             float* __restrict__ zp,
             const float* __restrict__ Wq, const float* __restrict__ Wk,
             unsigned short* __restrict__ WqT_i, unsigned short* __restrict__ WkT_i,
             const float* __restrict__ Wih, const float* __restrict__ Whh,
             const float* __restrict__ sl,  const float* __restrict__ Wv,
             unsigned short* __restrict__ Wihb, unsigned short* __restrict__ Whhb,
             unsigned short* __restrict__ slb,  unsigned short* __restrict__ Wvb)
{
    if (blockIdx.x < 2048) {
        const int i = blockIdx.x * 256 + threadIdx.x;
        fl4 z = {0.f, 0.f, 0.f, 0.f};
        *(fl4*)(zp + (long)i * 4) = z;
        return;
    }
    if (blockIdx.x < 2056) {
        constexpr int NB = 1024;
        const int b = (blockIdx.x - 2048) * 4 + (threadIdx.x >> 6);
        const int lane = threadIdx.x & 63;
        if (b >= 32) return;
        const int* mrow = mask + b * NB;
        int loc[16]; int lsum = 0;
#pragma unroll
        for (int i = 0; i < 16; ++i) { loc[i] = mrow[lane * 16 + i] != 0; lsum += loc[i]; }
        int pre = lsum;
#pragma unroll
        for (int o = 1; o < 64; o <<= 1) {
            int t = __shfl_up(pre, o);
            if (lane >= o) pre += t;
        }
        const int total = __shfl(pre, 63);
        pre -= lsum;
        int* ib = idx + b * NB;
        int p = pre;
#pragma unroll
        for (int i = 0; i < 16; ++i) if (loc[i]) ib[p++] = lane * 16 + i;
        if (lane == 0) {
            cnt[b] = total;
            int cp = (total + 63) & ~63;
            cpad[b] = cp < 64 ? 64 : cp;
        }
        return;
    }
    if (blockIdx.x < 6664) {
        constexpr int S = 768 * 768;
        const int o = (blockIdx.x - 2056) * 256 + threadIdx.x;
        if (o >= 2 * S) return;
        const float* x; unsigned short* y; int i;
        if (o < S) { x = Wq; y = WqT_i; i = o; }
        else       { x = Wk; y = WkT_i; i = o - S; }
        const int e = i / 768, d = i - e * 768;
        const float v = x[d * 768 + e];
        const unsigned short h = f2bf(v);
        y[(long)e * 1536 + d]       = h;
        y[(long)e * 1536 + 768 + d] = f2bf(v - bf2f(h));
        return;
    }
    // conv2 segment
    constexpr int S1 = 3 * 768 * 768;
    constexpr int S2 = S1 + 3 * 768 * 768;
    constexpr int S3 = S2 + 32 * 64 * 768;
    constexpr int S4 = S3 + 768 * 768;
    const int i = ((blockIdx.x - 6664) * 256 + threadIdx.x) * 4;
    if (i >= S4) return;
    const float* src; unsigned short* dst; int off;
    if (i < S1)      { src = Wih; dst = Wihb; off = i; }
    else if (i < S2) { src = Whh; dst = Whhb; off = i - S1; }
    else if (i < S3) { src = sl;  dst = slb;  off = i - S2; }
    else             { src = Wv;  dst = Wvb;  off = i - S3; }
    fl4 v = *(const fl4*)(src + off);
    u16x4 o;
#pragma unroll
    for (int j = 0; j < 4; ++j) o[j] = f2bf(v[j]);
    *(u16x4*)(dst + off) = o;
}

// ---------------------------------------------------------------------------
// Split-bf16 3-pass GEMM over row-interleaved A and B (split out).
template<int BM, int BN, int WAVES_M, int WAVES_N>
__global__ __launch_bounds__(256)
void gemm_bt3s(const unsigned short* __restrict__ AB, const unsigned short* __restrict__ BB,
               unsigned short* __restrict__ out1,
               int N, int K, long sA, long sB, float alpha)
{
    constexpr int BK = 32;
    constexpr int WM = BM / WAVES_M, WN = BN / WAVES_N;
    constexpr int MT = WM / 16, NT = WN / 16;
    __shared__ alignas(16) unsigned short Ash[BM * BK], Asl[BM * BK];
    __shared__ alignas(16) unsigned short Bsh[BN * BK], Bsl[BN * BK];

    const int bz = blockIdx.z;
    const int row0 = blockIdx.y * BM, col0 = blockIdx.x * BN;
    AB += (long)bz * sA;
    BB += (long)bz * sB;
    const int tid = threadIdx.x, l = tid & 63, w = tid >> 6;
    const int wm = w / WAVES_N, wn = w % WAVES_N;
    const int fr = l & 15, fq = l >> 4;

    f32x4 acc[MT][NT] = {};
    constexpr int ACALLS = (BM * BK) / (256 * 8);
    constexpr int BCALLS = (BN * BK) / (256 * 8);

    for (int kt = 0; kt < K; kt += BK) {
#pragma unroll
        for (int c = 0; c < ACALLS; ++c) {
            const int e = (c * 256 + tid) * 8;
            const long rb = (long)(row0 + (e >> 5)) * (2 * K) + kt + (e & 31);
            gload_lds16(AB + rb, &Ash[e]);
            gload_lds16(AB + rb + K, &Asl[e]);
        }
#pragma unroll
        for (int c = 0; c < BCALLS; ++c) {
            const int e = (c * 256 + tid) * 8;
            const long rb = (long)(col0 + (e >> 5)) * (2 * K) + kt + (e & 31);
            gload_lds16(BB + rb, &Bsh[e]);
            gload_lds16(BB + rb + K, &Bsl[e]);
        }
        __syncthreads();

        bf16x8 afh[MT], afl[MT], bfh[NT], bfl[NT];
#pragma unroll
        for (int m = 0; m < MT; ++m) {
            const int o = (wm * WM + m * 16 + fr) * BK + fq * 8;
            afh[m] = __builtin_bit_cast(bf16x8, *(const u16x8*)&Ash[o]);
            afl[m] = __builtin_bit_cast(bf16x8, *(const u16x8*)&Asl[o]);
        }
#pragma unroll
        for (int n = 0; n < NT; ++n) {
            const int o = (wn * WN + n * 16 + fr) * BK + fq * 8;
            bfh[n] = __builtin_bit_cast(bf16x8, *(const u16x8*)&Bsh[o]);
            bfl[n] = __builtin_bit_cast(bf16x8, *(const u16x8*)&Bsl[o]);
        }
#pragma unroll
        for (int m = 0; m < MT; ++m)
#pragma unroll
            for (int n = 0; n < NT; ++n) {
                acc[m][n] = __builtin_amdgcn_mfma_f32_16x16x32_bf16(afh[m], bfh[n], acc[m][n], 0, 0, 0);
                acc[m][n] = __builtin_amdgcn_mfma_f32_16x16x32_bf16(afh[m], bfl[n], acc[m][n], 0, 0, 0);
                acc[m][n] = __builtin_amdgcn_mfma_f32_16x16x32_bf16(afl[m], bfh[n], acc[m][n], 0, 0, 0);
            }
        __syncthreads();
    }

#pragma unroll
    for (int m = 0; m < MT; ++m) {
        const int gr = row0 + wm * WM + m * 16 + fq * 4;
#pragma unroll
        for (int n = 0; n < NT; ++n) {
            const int gc = col0 + wn * WN + n * 16 + fr;
#pragma unroll
            for (int j = 0; j < 4; ++j) {
                const float v = acc[m][n][j] * alpha;
                const long rb = (long)(gr + j) * (2 * N) + gc;
                const unsigned short h = f2bf(v);
                out1[rb] = h;
                out1[rb + N] = f2bf(v - bf2f(h));
            }
        }
    }
}

// ---------------------------------------------------------------------------
// FUSED logits-GEMM + normmax. Grid (N/64, B).
__global__ __launch_bounds__(256)
void logits_normmax(const unsigned short* __restrict__ qk_i,
                    const unsigned short* __restrict__ f_i,
                    const int* __restrict__ idx, const int* __restrict__ cnt,
                    const int* __restrict__ cpad,
                    float* __restrict__ attn_f32, unsigned short* __restrict__ attn_b16)
{
    constexpr int BK = 32, K = 768, C = 64, N = 1024;
    constexpr float alpha = 0.03608439182435161f;   // 1/sqrt(768)
    const int b = blockIdx.y;
    const int col0 = blockIdx.x * 64;
    if (col0 >= cpad[b]) return;

    __shared__ alignas(16) unsigned short Ash[64 * BK], Asl[64 * BK];
    __shared__ alignas(16) unsigned short Bsh[64 * BK], Bsl[64 * BK];
    __shared__ float lgS[64][65];

    const unsigned short* AB = qk_i + (long)b * C * 2 * K;
    const unsigned short* BB = f_i + (long)b * N * 2 * K;
    const int tid = threadIdx.x, l = tid & 63, w = tid >> 6;
    const int wm = w >> 1, wn = w & 1;
    const int fr = l & 15, fq = l >> 4;

    f32x4 acc[2][2] = {};

    for (int kt = 0; kt < K; kt += BK) {
        {
            const int e = tid * 8;
            const long ra = (long)(e >> 5) * (2 * K) + kt + (e & 31);
            gload_lds16(AB + ra, &Ash[e]);
            gload_lds16(AB + ra + K, &Asl[e]);
            const long rb = (long)(col0 + (e >> 5)) * (2 * K) + kt + (e & 31);
            gload_lds16(BB + rb, &Bsh[e]);
            gload_lds16(BB + rb + K, &Bsl[e]);
        }
        __syncthreads();

        bf16x8 afh[2], afl[2], bfh[2], bfl[2];
#pragma unroll
        for (int m = 0; m < 2; ++m) {
            const int o = (wm * 32 + m * 16 + fr) * BK + fq * 8;
            afh[m] = __builtin_bit_cast(bf16x8, *(const u16x8*)&Ash[o]);
            afl[m] = __builtin_bit_cast(bf16x8, *(const u16x8*)&Asl[o]);
        }
#pragma unroll
        for (int n = 0; n < 2; ++n) {
            const int o = (wn * 32 + n * 16 + fr) * BK + fq * 8;
            bfh[n] = __builtin_bit_cast(bf16x8, *(const u16x8*)&Bsh[o]);
            bfl[n] = __builtin_bit_cast(bf16x8, *(const u16x8*)&Bsl[o]);
        }
#pragma unroll
        for (int m = 0; m < 2; ++m)
#pragma unroll
            for (int n = 0; n < 2; ++n) {
                acc[m][n] = __builtin_amdgcn_mfma_f32_16x16x32_bf16(afh[m], bfh[n], acc[m][n], 0, 0, 0);
                acc[m][n] = __builtin_amdgcn_mfma_f32_16x16x32_bf16(afh[m], bfl[n], acc[m][n], 0, 0, 0);
                acc[m][n] = __builtin_amdgcn_mfma_f32_16x16x32_bf16(afl[m], bfh[n], acc[m][n], 0, 0, 0);
            }
        __syncthreads();
    }

#pragma unroll
    for (int m = 0; m < 2; ++m) {
        const int lr = wm * 32 + m * 16 + fq * 4;
#pragma unroll
        for (int n = 0; n < 2; ++n) {
            const int lc = wn * 32 + n * 16 + fr;
#pragma unroll
            for (int j = 0; j < 4; ++j) lgS[lr + j][lc] = acc[m][n][j] * alpha;
        }
    }
    __syncthreads();

    const int jl = w * 16 + (l & 15);
    const int cb = (l >> 4) * 16;
    const int j = col0 + jl;
    const bool valid = j < cnt[b];

    float z[16];
#pragma unroll
    for (int i = 0; i < 16; ++i) z[i] = valid ? lgS[cb + i][jl] : 0.f;

    float mx = z[0];
#pragma unroll
    for (int i = 1; i < 16; ++i) mx = fmaxf(mx, z[i]);
    mx = fmaxf(mx, __shfl_xor(mx, 16));
    mx = fmaxf(mx, __shfl_xor(mx, 32));

    float lo = mx - 1.f, hi = mx;
    for (int it = 0; it < 34; ++it) {
        const float tau = 0.5f * (lo + hi);
        float f = 0.f;
#pragma unroll
        for (int i = 0; i < 16; ++i) {
            const float u = fmaxf(z[i] - tau, 0.f);
            f += u * sqrt_raw(sqrt_raw(u));       // u^(5/4)
        }
        f += __shfl_xor(f, 16);
        f += __shfl_xor(f, 32);
        if (f >= 1.f) lo = tau; else hi = tau;
    }
    const float tau = 0.5f * (lo + hi);
    float sv[16]; float ss = 0.f;
#pragma unroll
    for (int i = 0; i < 16; ++i) {
        const float u = fmaxf(z[i] - tau, 0.f);
        sv[i] = sqrt_raw(sqrt_raw(u));            // u^(1/4)
        ss += sv[i];
    }
    ss += __shfl_xor(ss, 16);
    ss += __shfl_xor(ss, 32);
    const float inv = 1.f / ss;
    const long base = (long)b * C * N + j;
    const int n_orig = valid ? idx[(b << 10) + j] : 0;
#pragma unroll
    for (int i = 0; i < 16; ++i) {
        const float a = valid ? sv[i] * inv : 0.f;
        attn_b16[base + (long)(cb + i) * N] = f2bf(a);
        if (valid) attn_f32[(long)b * C * N + (long)(cb + i) * N + n_orig] = a;
    }
}

// ---------------------------------------------------------------------------
// Plain bf16 GEMM: C[M,N] = alpha * A[M,K] @ B[N,K]^T
template<int BM, int BN, int WAVES_M, int WAVES_N, bool OUT_F32>
__global__ __launch_bounds__(256)
void gemm_bt(const unsigned short* __restrict__ A,
             const unsigned short* __restrict__ B,
             void* __restrict__ Cv,
             int N, int K, long sA, long sB, long sC, float alpha)
{
    constexpr int BK = 32;
    constexpr int WM = BM / WAVES_M, WN = BN / WAVES_N;
    constexpr int MT = WM / 16, NT = WN / 16;
    __shared__ alignas(16) unsigned short As[BM * BK];
    __shared__ alignas(16) unsigned short Bs[BN * BK];

    const int bz = blockIdx.z;
    A += (long)bz * sA;
    B += (long)bz * sB;
    const int row0 = blockIdx.y * BM, col0 = blockIdx.x * BN;
    const int tid = threadIdx.x, l = tid & 63, w = tid >> 6;
    const int wm = w / WAVES_N, wn = w % WAVES_N;
    const int fr = l & 15, fq = l >> 4;

    f32x4 acc[MT][NT] = {};
    constexpr int ACALLS = (BM * BK) / (256 * 8);
    constexpr int BCALLS = (BN * BK) / (256 * 8);

    for (int kt = 0; kt < K; kt += BK) {
#pragma unroll
        for (int c = 0; c < ACALLS; ++c) {
            const int e = (c * 256 + tid) * 8;
            gload_lds16(A + (long)(row0 + (e >> 5)) * K + kt + (e & 31), &As[e]);
        }
#pragma unroll
        for (int c = 0; c < BCALLS; ++c) {
            const int e = (c * 256 + tid) * 8;
            gload_lds16(B + (long)(col0 + (e >> 5)) * K + kt + (e & 31), &Bs[e]);
        }
        __syncthreads();

        bf16x8 af[MT], bfr[NT];
#pragma unroll
        for (int m = 0; m < MT; ++m)
            af[m] = __builtin_bit_cast(bf16x8, *(const u16x8*)&As[(wm * WM + m * 16 + fr) * BK + fq * 8]);
#pragma unroll
        for (int n = 0; n < NT; ++n)
            bfr[n] = __builtin_bit_cast(bf16x8, *(const u16x8*)&Bs[(wn * WN + n * 16 + fr) * BK + fq * 8]);
#pragma unroll
        for (int m = 0; m < MT; ++m)
#pragma unroll
            for (int n = 0; n < NT; ++n)
                acc[m][n] = __builtin_amdgcn_mfma_f32_16x16x32_bf16(af[m], bfr[n], acc[m][n], 0, 0, 0);
        __syncthreads();
    }

#pragma unroll
    for (int m = 0; m < MT; ++m) {
        const int gr = row0 + wm * WM + m * 16 + fq * 4;
#pragma unroll
        for (int n = 0; n < NT; ++n) {
            const int gc = col0 + wn * WN + n * 16 + fr;
#pragma unroll
            for (int j = 0; j < 4; ++j) {
                const float v = acc[m][n][j] * alpha;
                if (OUT_F32) ((float*)Cv)[(long)bz * sC + (long)(gr + j) * N + gc] = v;
                else ((unsigned short*)Cv)[(long)bz * sC + (long)(gr + j) * N + gc] = f2bf(v);
            }
        }
    }
}

// ---------------------------------------------------------------------------
// Fused gate-GEMM + GRU (K=768), 256 threads, 64x64 tiles (round-18 config).
__global__ __launch_bounds__(256)
void gemm_gru(const unsigned short* __restrict__ updb, const unsigned short* __restrict__ slb,
              const unsigned short* __restrict__ Wihb, const unsigned short* __restrict__ Whhb,
              const float* __restrict__ b_ih, const float* __restrict__ b_hh,
              const float* __restrict__ h, float* __restrict__ out)
{
    constexpr int BK = 32, Kd = 768, Dd = 768;
    __shared__ alignas(16) unsigned short Au[64 * BK], As[64 * BK];
    __shared__ alignas(16) unsigned short Bi[3][64 * BK], Bh[3][64 * BK];

    const int row0 = blockIdx.y * 64, col0 = blockIdx.x * 64;
    const int tid = threadIdx.x, l = tid & 63, w = tid >> 6;
    const int wm = w >> 1, wn = w & 1;
    const int fr = l & 15, fq = l >> 4;

    f32x4 ai[3][2][2] = {}, ah[3][2][2] = {};

    for (int kt = 0; kt < Kd; kt += BK) {
        {
            const int e = tid * 8;
            const long rb = (long)(row0 + (e >> 5)) * Kd + kt + (e & 31);
            gload_lds16(updb + rb, &Au[e]);
            gload_lds16(slb + rb, &As[e]);
#pragma unroll
            for (int g = 0; g < 3; ++g) {
                const long wb = (long)(g * Dd + col0 + (e >> 5)) * Kd + kt + (e & 31);
                gload_lds16(Wihb + wb, &Bi[g][e]);
                gload_lds16(Whhb + wb, &Bh[g][e]);
            }
        }
        __syncthreads();

        bf16x8 au[2], as_[2], bi[3][2], bh[3][2];
#pragma unroll
        for (int m = 0; m < 2; ++m) {
            const int o = (wm * 32 + m * 16 + fr) * BK + fq * 8;
            au[m]  = __builtin_bit_cast(bf16x8, *(const u16x8*)&Au[o]);
            as_[m] = __builtin_bit_cast(bf16x8, *(const u16x8*)&As[o]);
        }
#pragma unroll
        for (int n = 0; n < 2; ++n) {
            const int o = (wn * 32 + n * 16 + fr) * BK + fq * 8;
#pragma unroll
            for (int g = 0; g < 3; ++g) {
                bi[g][n] = __builtin_bit_cast(bf16x8, *(const u16x8*)&Bi[g][o]);
                bh[g][n] = __builtin_bit_cast(bf16x8, *(const u16x8*)&Bh[g][o]);
            }
        }
#pragma unroll
        for (int g = 0; g < 3; ++g)
#pragma unroll
            for (int m = 0; m < 2; ++m)
#pragma unroll
                for (int n = 0; n < 2; ++n) {
                    ai[g][m][n] = __builtin_amdgcn_mfma_f32_16x16x32_bf16(au[m],  bi[g][n], ai[g][m][n], 0, 0, 0);
                    ah[g][m][n] = __builtin_amdgcn_mfma_f32_16x16x32_bf16(as_[m], bh[g][n], ah[g][m][n], 0, 0, 0);
                }
        __syncthreads();
    }

#pragma unroll
    for (int m = 0; m < 2; ++m) {
        const int gr = row0 + wm * 32 + m * 16 + fq * 4;
#pragma unroll
        for (int n = 0; n < 2; ++n) {
            const int gc = col0 + wn * 32 + n * 16 + fr;
            const float bir = b_ih[gc],        bhr = b_hh[gc];
            const float biz = b_ih[Dd + gc],   bhz = b_hh[Dd + gc];
            const float bin = b_ih[2*Dd + gc], bhn = b_hh[2*Dd + gc];
#pragma unroll
            for (int j = 0; j < 4; ++j) {
                const float r  = 1.f / (1.f + expf(-(ai[0][m][n][j] + bir + ah[0][m][n][j] + bhr)));
                const float zg = 1.f / (1.f + expf(-(ai[1][m][n][j] + biz + ah[1][m][n][j] + bhz)));
                const float ng = tanhf(ai[2][m][n][j] + bin + r * (ah[2][m][n][j] + bhn));
                const long idx = (long)(gr + j) * Dd + gc;
                out[idx] = (1.f - zg) * ng + zg * h[idx];
            }
        }
    }
}

// ---------------------------------------------------------------------------
// P GEMM, compacted-K, fused row-sum normalization.
template<int BM, int BN, int WAVES_M, int WAVES_N>
__global__ __launch_bounds__(256)
void gemm_nt_rs(const unsigned short* __restrict__ A,
                const unsigned short* __restrict__ Bm,
                unsigned short* __restrict__ C,
                const int* __restrict__ cpad,
                int N, int Kmax, long sA, long sB, long sC)
{
    constexpr int BK = 32;
    constexpr int WM = BM / WAVES_M, WN = BN / WAVES_N;
    constexpr int MT = WM / 16, NT = WN / 16;
    __shared__ alignas(16) unsigned short As[BM * BK];
    __shared__ alignas(16) unsigned short Bs[BN * BK];
    __shared__ float rsums[BM];

    const int bz = blockIdx.z;
    const int Keff = cpad[bz];
    A += (long)bz * sA;
    Bm += (long)bz * sB;
    const int row0 = blockIdx.y * BM, col0 = blockIdx.x * BN;
    const int tid = threadIdx.x, l = tid & 63, w = tid >> 6;
    const int wm = w / WAVES_N, wn = w % WAVES_N;
    const int fr = l & 15, fq = l >> 4;

    f32x4 acc[MT][NT] = {};
    float rsum = 0.f;
    constexpr int ACALLS = (BM * BK) / (256 * 8);
    constexpr int TPR = BN / 8;
    constexpr int RPP = 256 / TPR;
    const int br = tid / TPR, bc8 = (tid % TPR) * 8;

    for (int kt = 0; kt < Keff; kt += BK) {
#pragma unroll
        for (int c = 0; c < ACALLS; ++c) {
            const int e = (c * 256 + tid) * 8;
            gload_lds16(A + (long)(row0 + (e >> 5)) * Kmax + kt + (e & 31), &As[e]);
        }
#pragma unroll
        for (int p = 0; p < BK / RPP; ++p) {
            const int r = p * RPP + br;
            u16x8 vv = *(const u16x8*)(Bm + (long)(kt + r) * (2 * N) + col0 + bc8);
#pragma unroll
            for (int j = 0; j < 8; ++j) Bs[(bc8 + j) * BK + r] = vv[j];
        }
        __syncthreads();

        if (tid < BM) {
#pragma unroll
            for (int kk = 0; kk < BK / 8; ++kk) {
                u16x8 vv = *(const u16x8*)&As[tid * BK + kk * 8];
#pragma unroll
                for (int j = 0; j < 8; ++j) rsum += bf2f(vv[j]);
            }
        }

        bf16x8 af[MT], bfr[NT];
#pragma unroll
        for (int m = 0; m < MT; ++m)
            af[m] = __builtin_bit_cast(bf16x8, *(const u16x8*)&As[(wm * WM + m * 16 + fr) * BK + fq * 8]);
#pragma unroll
        for (int n = 0; n < NT; ++n)
            bfr[n] = __builtin_bit_cast(bf16x8, *(const u16x8*)&Bs[(wn * WN + n * 16 + fr) * BK + fq * 8]);
#pragma unroll
        for (int m = 0; m < MT; ++m)
#pragma unroll
            for (int n = 0; n < NT; ++n)
                acc[m][n] = __builtin_amdgcn_mfma_f32_16x16x32_bf16(af[m], bfr[n], acc[m][n], 0, 0, 0);
        __syncthreads();
    }

    if (tid < BM) rsums[tid] = rsum;
    __syncthreads();

#pragma unroll
    for (int m = 0; m < MT; ++m) {
        const int lr = wm * WM + m * 16 + fq * 4;
        const int gr = row0 + lr;
#pragma unroll
        for (int n = 0; n < NT; ++n) {
            const int gc = col0 + wn * WN + n * 16 + fr;
#pragma unroll
            for (int j = 0; j < 4; ++j) {
                const float inv = 1.f / (rsums[lr + j] + 1e-8f);
                C[(long)bz * sC + (long)(gr + j) * N + gc] = f2bf(acc[m][n][j] * inv);
            }
        }
    }
}

// ---------------------------------------------------------------------------
// Fused, mask-compacted LayerNorm (features + slots), f32 -> interleaved split.
__global__ __launch_bounds__(256)
void ln_fused_c(const float* __restrict__ xf, const float* __restrict__ gf,
                const float* __restrict__ bf,
                unsigned short* __restrict__ fi,
                const float* __restrict__ xs, const float* __restrict__ gs,
                const float* __restrict__ bs,
                unsigned short* __restrict__ si,
                const int* __restrict__ idx, const int* __restrict__ cnt,
                const int* __restrict__ cpad, int nrows_f)
{
    constexpr int D = 768;
    const int lane = threadIdx.x & 63;
    long row = (long)blockIdx.x * 4 + (threadIdx.x >> 6);
    const float *x, *g, *bb_;
    long srow;
    if (row < nrows_f) {
        const int b = (int)(row >> 10), j = (int)(row & 1023);
        if (j >= cpad[b]) return;
        srow = row;
        unsigned short* yr = fi + srow * (2 * D);
        if (j >= cnt[b]) {
            u16x8 z = {};
            unsigned short* p = yr + lane * 24;
            *(u16x8*)p = z; *(u16x8*)(p + 8) = z; *(u16x8*)(p + 16) = z;
            return;
        }
        const int n = idx[(b << 10) + j];
        x = xf + ((long)(b << 10) + n) * D;
        g = gf; bb_ = bf;
    } else {
        srow = row - nrows_f;
        x = xs + srow * D;
        g = gs; bb_ = bs;
    }

    const int eA = lane * 8;
    const int eB = 512 + lane * 8;
    float v[16];
    {
        fl4 a = *(const fl4*)(x + eA);
        fl4 b = *(const fl4*)(x + eA + 4);
#pragma unroll
        for (int j = 0; j < 4; ++j) { v[j] = a[j]; v[4 + j] = b[j]; }
    }
    if (lane < 32) {
        fl4 a = *(const fl4*)(x + eB);
        fl4 b = *(const fl4*)(x + eB + 4);
#pragma unroll
        for (int j = 0; j < 4; ++j) { v[8 + j] = a[j]; v[12 + j] = b[j]; }
    }
    float s = 0.f, s2 = 0.f;
#pragma unroll
    for (int j = 0; j < 8; ++j) { s += v[j]; s2 += v[j] * v[j]; }
    if (lane < 32) {
#pragma unroll
        for (int j = 8; j < 16; ++j) { s += v[j]; s2 += v[j] * v[j]; }
    }
#pragma unroll
    for (int o = 1; o < 64; o <<= 1) { s += __shfl_xor(s, o); s2 += __shfl_xor(s2, o); }
    const float mu  = s / (float)D;
    const float var = s2 / (float)D - mu * mu;
    const float r   = rsqrtf(var + 1e-5f);

    unsigned short* yr = (row < nrows_f ? fi : si) + srow * (2 * D);
    {
        fl4 g0 = *(const fl4*)(g + eA), g1 = *(const fl4*)(g + eA + 4);
        fl4 b0 = *(const fl4*)(bb_ + eA), b1 = *(const fl4*)(bb_ + eA + 4);
        u16x8 oh, ol;
#pragma unroll
        for (int j = 0; j < 8; ++j) {
            const float gg = (j < 4) ? g0[j] : g1[j - 4];
            const float be = (j < 4) ? b0[j] : b1[j - 4];
            const float yv = (v[j] - mu) * r * gg + be;
            oh[j] = f2bf(yv);
            ol[j] = f2bf(yv - bf2f(oh[j]));
        }
        *(u16x8*)(yr + eA) = oh;
        *(u16x8*)(yr + D + eA) = ol;
    }
    if (lane < 32) {
        fl4 g0 = *(const fl4*)(g + eB), g1 = *(const fl4*)(g + eB + 4);
        fl4 b0 = *(const fl4*)(bb_ + eB), b1 = *(const fl4*)(bb_ + eB + 4);
        u16x8 oh, ol;
#pragma unroll
        for (int j = 0; j < 8; ++j) {
            const float gg = (j < 4) ? g0[j] : g1[j - 4];
            const float be = (j < 4) ? b0[j] : b1[j - 4];
            const float yv = (v[8 + j] - mu) * r * gg + be;
            oh[j] = f2bf(yv);
            ol[j] = f2bf(yv - bf2f(oh[j]));
        }
        *(u16x8*)(yr + eB) = oh;
        *(u16x8*)(yr + D + eB) = ol;
    }
}

extern "C" void kernel_launch(void* const* d_in, const int* in_sizes, int n_in,
                              void* d_out, int out_size, void* d_ws, size_t ws_size,
                              hipStream_t stream)
{
    const float* features = (const float*)d_in[0];
    const float* slots    = (const float*)d_in[1];
    const int*   mask     = (const int*)d_in[2];
    const float* lnf_g = (const float*)d_in[3];
    const float* lnf_b = (const float*)d_in[4];
    const float* lns_g = (const float*)d_in[5];
    const float* lns_b = (const float*)d_in[6];
    const float* Wk  = (const float*)d_in[7];
    const float* Wv  = (const float*)d_in[8];
    const float* Wq  = (const float*)d_in[9];
    const float* Wih = (const float*)d_in[10];
    const float* Whh = (const float*)d_in[11];
    const float* bih = (const float*)d_in[12];
    const float* bhh = (const float*)d_in[13];

    constexpr int B = 32, N = 1024, C = 64, D = 768;
    char* ws = (char*)d_ws;
    // ---- workspace layout, peak ~132.0 MB
    unsigned short* f_i  = (unsigned short*)(ws + 0);          // compacted f, 100,663,296
    unsigned short* updb = (unsigned short*)(ws + 57671680);   // [upd gemm .. gru] (f_i dead)
    unsigned short* Wihb = (unsigned short*)(ws + 100663296);  //  3,538,944
    unsigned short* Whhb = (unsigned short*)(ws + 104202240);  //  3,538,944
    unsigned short* Wvb  = (unsigned short*)(ws + 107741184);  //  1,179,648 -> 108,920,832
    unsigned short* s_i    = (unsigned short*)(ws + 109051904); //  6,291,456 [LN .. qk gemm]
    unsigned short* ab16   = (unsigned short*)(ws + 109051904); //  4,194,304 (s_i dead)
    unsigned short* qk_i   = (unsigned short*)(ws + 115343360); //  6,291,456 [qk .. logits]
    unsigned short* Pbf    = (unsigned short*)(ws + 115343360); //  3,145,728 (qk_i dead)
    unsigned short* WqT_i  = (unsigned short*)(ws + 121634816); //  2,359,296
    unsigned short* WkT_i  = (unsigned short*)(ws + 123994112); //  2,359,296
    unsigned short* M_i    = (unsigned short*)(ws + 126353408); //  2,359,296
    int*            idx    = (int*)(ws + 128712704);            //    131,072
    int*            cnt    = (int*)(ws + 128843776);            //        128
    int*            cpad   = (int*)(ws + 128843904);            //        128
    unsigned short* slb    = (unsigned short*)(ws + 128844032); //  3,145,728 -> 131,989,760

    float* out_slots = (float*)d_out;
    float* out_attn  = out_slots + (long)B * C * D;

    // preproc: zfill + mask scan + Wq/Wk transpose-split + GRU-weight convert
    preproc<<<12232, 256, 0, stream>>>(
        mask, idx, cnt, cpad, out_attn, Wq, Wk, WqT_i, WkT_i,
        Wih, Whh, slots, Wv, Wihb, Whhb, slb, Wvb);

    // compacted LN (features) + LN (slots)
    ln_fused_c<<<(B * N + B * C) / 4, 256, 0, stream>>>(
        features, lnf_g, lnf_b, f_i,
        slots, lns_g, lns_b, s_i,
        idx, cnt, cpad, B * N);

    // M[j,i] = sum_k Wk[k,j]*Wq[k,i]  [768 x 768], interleaved out
    gemm_bt3s<64, 64, 2, 2><<<dim3(D / 64, D / 64, 1), 256, 0, stream>>>(
        WkT_i, WqT_i, M_i, D, D, 0, 0, 1.f);
    // qk = s @ M^T   [2048 x 768], interleaved out
    gemm_bt3s<64, 64, 2, 2><<<dim3(D / 64, (B * C) / 64, 1), 256, 0, stream>>>(
        s_i, M_i, qk_i, D, D, 0, 0, 1.f);

    // FUSED logits + normmax -> scattered f32 attn (d_out) + compacted bf16
    logits_normmax<<<dim3(N / 64, B), 256, 0, stream>>>(
        qk_i, f_i, idx, cnt, cpad, out_attn, ab16);

    // P[b] = diag(1/(rowsum+eps)) * attñ_b @ f̃_b(hi)   [64 x 768], K=cpad(b)
    gemm_nt_rs<64, 64, 2, 2><<<dim3(D / 64, 1, B), 256, 0, stream>>>(
        ab16, f_i, Pbf, cpad, D, N, (long)C * N, (long)N * 2 * D, (long)C * D);

    // upd = P @ Wv^T   [2048 x 768]
    gemm_bt<64, 64, 2, 2, false><<<dim3(D / 64, (B * C) / 64, 1), 256, 0, stream>>>(
        Pbf, Wvb, updb, D, D, 0, 0, 0, 1.f);

    // fused gate-GEMM + GRU -> out_slots (64x64 tiles, 256 threads, 384 blocks)
    gemm_gru<<<dim3(D / 64, (B * C) / 64), 256, 0, stream>>>(
        updb, slb, Wihb, Whhb, bih, bhh, slots, out_slots);
}